// Round 4
// baseline (973.067 us; speedup 1.0000x reference)
//
#include <hip/hip_runtime.h>
#include <hip/hip_bf16.h>
#include <cstdint>
#include <cstddef>

// out[b,o] = sum_i silu(x[b,i])*BW[o,i] + sum_{i,c} exp(-5*(x[b,i]-g_c)^2)*SW[o,i,c]
// Round 7: GEMM phase-merge 8 -> 4 (32 MFMA per barrier-pair). Per-phase accounting
// at r3: MFMA pipe 621 cyc, LDS pipe ~700 cyc, measured 1068 -> ~35% barrier/resync
// overhead at 16 barriers/iter. Merged form keeps ALL 8 stage-issue points and both
// vmcnt(6) points at their exact old stream positions (ledger bit-identical); only
// barrier count halves. Expansions merged into one launch (saves a gap); their
// round-3 rewrite showed they're already at BW floor.

#define KIN 2048
#define NOUT 2048
#define BATCH 16384
#define KEXP 12288          // 2048 * 6
#define NKT 192             // KEXP / 64

typedef __bf16 bf16x8 __attribute__((ext_vector_type(8)));
typedef float f32x4 __attribute__((ext_vector_type(4)));
typedef unsigned short u16x4 __attribute__((ext_vector_type(4)));

__device__ __forceinline__ unsigned short f2bf(float f) {
    union { float f; uint32_t u; } v; v.f = f;
    return (unsigned short)((v.u + 0x7FFFu + ((v.u >> 16) & 1u)) >> 16);
}

__device__ __forceinline__ void load_lds16(const void* gptr, void* lptr) {
    __builtin_amdgcn_global_load_lds(
        (const __attribute__((address_space(1))) unsigned int*)gptr,
        (__attribute__((address_space(3))) unsigned int*)lptr,
        16, 0, 0);
}

// ---------------- merged expansion: one dispatch for Wexp + Aexp ----------------
// bid < NOUT: expand W row bid. bid >= NOUT: expand A row bid-NOUT.
// Both: compute in regs, stage 24 KB row in LDS, write 6x16B/lane contiguous.
__global__ __launch_bounds__(256)
void expand_ab(const float* __restrict__ X, const float* __restrict__ BW,
               const float* __restrict__ SW, __bf16* __restrict__ Aexp,
               __bf16* __restrict__ Wexp)
{
    __shared__ __align__(16) __bf16 rowbuf[KEXP];   // 24 KB
    const int bid = blockIdx.x;
    const int tid = threadIdx.x;

    if (bid >= NOUT) {
        // ---- A row: RBF ratio recurrence (2 exps for 5 basis values) + silu ----
        const int row = bid - NOUT;
        const float* xrow = X + (size_t)row * KIN;
        // k_c = exp(-5*g_c - 1.25), g_c = -1 + 0.5c
        const float K0 = 42.521082000062783f;   // exp(3.75)
        const float K1 = 3.4903429574597902f;   // exp(1.25)
        const float K2 = 0.2865047968601901f;   // exp(-1.25)
        const float K3 = 0.023517745856009107f; // exp(-3.75)
        #pragma unroll
        for (int s = 0; s < 2; ++s) {
            const f32x4 xv = *(const f32x4*)(xrow + (s * 256 + tid) * 4);
            float o[24];
            #pragma unroll
            for (int e = 0; e < 4; ++e) {
                const float xf = xv[e];
                const float d0 = xf + 1.0f;
                float b = __expf(-5.0f * d0 * d0);     // basis at g=-1
                const float s5 = __expf(5.0f * xf);    // ratio driver
                o[e * 6 + 0] = b;
                b *= s5 * K0; o[e * 6 + 1] = b;
                b *= s5 * K1; o[e * 6 + 2] = b;
                b *= s5 * K2; o[e * 6 + 3] = b;
                b *= s5 * K3; o[e * 6 + 4] = b;
                o[e * 6 + 5] = xf / (1.0f + __expf(-xf));
            }
            __bf16* dst = rowbuf + (s * 1024 + tid * 4) * 6;
            #pragma unroll
            for (int q = 0; q < 3; ++q) {
                bf16x8 v;
                #pragma unroll
                for (int t = 0; t < 8; ++t) v[t] = (__bf16)o[q * 8 + t];
                *(bf16x8*)(dst + q * 8) = v;
            }
        }
        __syncthreads();
        bf16x8* out = (bf16x8*)(Aexp + (size_t)row * KEXP);
        const bf16x8* lsrc = (const bf16x8*)rowbuf;
        #pragma unroll
        for (int t = 0; t < 6; ++t)
            out[tid + t * 256] = lsrc[tid + t * 256];
    } else {
        // ---- W row: interleave SW (5/elem) + BW (1/elem) ----
        const int orow = bid;
        #pragma unroll
        for (int s = 0; s < 2; ++s) {
            const int i0 = s * 1024 + tid * 4;
            const float* sb = SW + ((size_t)orow * KIN + i0) * 5;   // 20 floats
            const f32x4 bw = *(const f32x4*)(BW + (size_t)orow * KIN + i0);
            float sw[20];
            #pragma unroll
            for (int q = 0; q < 5; ++q) {
                const f32x4 v = *(const f32x4*)(sb + q * 4);
                sw[q * 4 + 0] = v.x; sw[q * 4 + 1] = v.y;
                sw[q * 4 + 2] = v.z; sw[q * 4 + 3] = v.w;
            }
            __bf16* dst = rowbuf + (size_t)i0 * 6;
            #pragma unroll
            for (int q = 0; q < 3; ++q) {
                bf16x8 v;
                #pragma unroll
                for (int t = 0; t < 8; ++t) {
                    const int e = (q * 8 + t) / 6;
                    const int c = (q * 8 + t) % 6;
                    v[t] = (c < 5) ? (__bf16)sw[e * 5 + c] : (__bf16)bw[e];
                }
                *(bf16x8*)(dst + q * 8) = v;
            }
        }
        __syncthreads();
        bf16x8* out = (bf16x8*)(Wexp + (size_t)orow * KEXP);
        const bf16x8* lsrc = (const bf16x8*)rowbuf;
        #pragma unroll
        for (int t = 0; t < 6; ++t)
            out[tid + t * 256] = lsrc[tid + t * 256];
    }
}

// ---------------- 256x256 4-phase GEMM: OUT[16384][2048] = Aexp * Wexp^T --------
// Per iteration: 2 K-tiles (BK=64), 4 merged phases of 32 MFMA each. Stage-issue
// points and vmcnt(6) placement identical to the validated 8-phase ledger; only
// the barrier count is halved (16 -> 8 per iteration).
//
// T1: blockIdx remapped (bid%8 = XCD) -> FETCH_SIZE 2.18 GB -> 600 MB (measured).
// LDS: [2buf][2kh][256 rows][4 chunks of 8 bf16] per matrix, XOR chunk swizzle,
// linear global_load_lds dest + pre-swizzled global source. Bank conflicts: 0.
//
// vmcnt ledger (2 loads per stage, oldest-first):
//   entering I: 6 in flight {B1klo,A1klo,B1khi}(kt 2t+1, staged prev III/IV).
//   I: +A1khi(kt1) +B0klo(sA); II: +A0klo(sA) +B0khi(sA), VM6 after B0khi
//      -> drains leftovers+A1khi (buf1 ready for III/IV).
//   III: +A0khi(sA) +B1klo(sB); IV: +A1klo(sB) +B1khi(sB), VM6 after B1khi
//      -> drains all 4 buf0 slots (ready for next I/II). Never vmcnt(0).
//   WAR: every mid-cluster stage targets a slot whose ds_reads drained before
//   the preceding MFMA half-cluster; phase-head stages target slots last read
//   before the previous closing barrier.
__global__ __launch_bounds__(512, 2)
void gemm8(const __bf16* __restrict__ A, const __bf16* __restrict__ W,
           float* __restrict__ OUT)
{
    __shared__ __align__(16) __bf16 LDS[65536];   // 128 KiB
    __bf16* LA = LDS;              // [2buf][2kh][8192 elems]
    __bf16* LB = LDS + 32768;

    const int tid  = threadIdx.x;
    const int lane = tid & 63;
    const int wave = tid >> 6;     // 0..7
    const int r    = lane & 15;
    const int quad = lane >> 4;
    const int wm   = wave >> 2;    // 0..1  (M)
    const int wn   = wave & 3;     // 0..3  (N)

    // T1 XCD-aware bijective swizzle: 512 blocks, 8 XCDs, chunk = 64.
    const int bid0 = blockIdx.x;
    const int bid  = (bid0 & 7) * 64 + (bid0 >> 3);
    const int mt  = bid >> 3;      // 64 m-tiles
    const int nt  = bid & 7;       // 8 n-tiles
    const int m0  = mt * 256;
    const int n0  = nt * 256;

    // ---- staging source addresses (per-lane, pre-swizzled) ----
    const int c0   = tid;                          // slot chunk ids 0..511
    const int c1   = tid + 512;                    // 512..1023
    const int row0 = c0 >> 2, row1 = c1 >> 2;      // slot rows 0..255
    const int j0   = (c0 & 3) ^ ((c0 >> 3) & 3);   // logical chunk for phys slot
    const int j1   = (c1 & 3) ^ ((c1 >> 3) & 3);
    const __bf16* srcA0 = A + (size_t)(m0 + row0) * KEXP + j0 * 8;
    const __bf16* srcA1 = A + (size_t)(m0 + row1) * KEXP + j1 * 8;
    const __bf16* srcB0 = W + (size_t)(n0 + row0) * KEXP + j0 * 8;
    const __bf16* srcB1 = W + (size_t)(n0 + row1) * KEXP + j1 * 8;

    // LDS stage destinations: wave-uniform base; HW adds lane*16B.
    const int dst0 = wave * 512;          // issue s=0 (elems)
    const int dst1 = 4096 + wave * 512;   // issue s=1

    // ---- fragment read bases (swizzled) ----
    const int swz = (quad ^ ((r >> 1) & 3)) * 8;
    const __bf16* a_rd = LA + (wm * 128 + r) * 32 + swz;
    const __bf16* b_rd = LB + (wn * 64 + r) * 32 + swz;

    f32x4 acc[8][4];
    #pragma unroll
    for (int i = 0; i < 8; ++i)
        #pragma unroll
        for (int j = 0; j < 4; ++j)
            acc[i][j] = (f32x4){0.0f, 0.0f, 0.0f, 0.0f};

    bf16x8 af0[4], af1[4], bf[4];

#define BARX() asm volatile("s_barrier" ::: "memory")
#define VM6()  asm volatile("s_waitcnt vmcnt(6)" ::: "memory")

#define STAGE_A(buf, kh, kt) do { \
    const size_t ko = (size_t)(kt) * 64 + (kh) * 32; \
    load_lds16(srcA0 + ko, LA + ((buf) * 2 + (kh)) * 8192 + dst0); \
    load_lds16(srcA1 + ko, LA + ((buf) * 2 + (kh)) * 8192 + dst1); } while (0)

#define STAGE_B(buf, kh, kt) do { \
    const size_t ko = (size_t)(kt) * 64 + (kh) * 32; \
    load_lds16(srcB0 + ko, LB + ((buf) * 2 + (kh)) * 8192 + dst0); \
    load_lds16(srcB1 + ko, LB + ((buf) * 2 + (kh)) * 8192 + dst1); } while (0)

#define READ_AF(arr, buf, ks, a) do { \
    const __bf16* p_ = a_rd + ((buf) * 2 + (ks)) * 8192 + (a) * 2048; \
    arr[0] = *(const bf16x8*)(p_); \
    arr[1] = *(const bf16x8*)(p_ + 512); \
    arr[2] = *(const bf16x8*)(p_ + 1024); \
    arr[3] = *(const bf16x8*)(p_ + 1536); } while (0)

#define READ_B(buf, ks) do { \
    const __bf16* p_ = b_rd + ((buf) * 2 + (ks)) * 8192; \
    bf[0] = *(const bf16x8*)(p_); \
    bf[1] = *(const bf16x8*)(p_ + 512); \
    bf[2] = *(const bf16x8*)(p_ + 1024); \
    bf[3] = *(const bf16x8*)(p_ + 1536); } while (0)

#define MFMA16(frag, a) do { \
    __builtin_amdgcn_s_setprio(1); \
    _Pragma("unroll") \
    for (int mi_ = 0; mi_ < 4; ++mi_) { \
        _Pragma("unroll") \
        for (int nj_ = 0; nj_ < 4; ++nj_) \
            acc[(a) * 4 + mi_][nj_] = __builtin_amdgcn_mfma_f32_16x16x32_bf16( \
                frag[mi_], bf[nj_], acc[(a) * 4 + mi_][nj_], 0, 0, 0); \
    } \
    __builtin_amdgcn_s_setprio(0); } while (0)

    // ---- prologue: K-tile 0 full (buf0) + 3 of K-tile 1 (buf1) = 14 loads ----
    STAGE_B(0, 0, 0); STAGE_A(0, 0, 0); STAGE_B(0, 1, 0); STAGE_A(0, 1, 0);
    STAGE_B(1, 0, 1); STAGE_A(1, 0, 1); STAGE_B(1, 1, 1);
    VM6();            // completes the 4 buf0 slots; leaves buf1's 3 in flight
    BARX();

    // ---- main loop: 96 iterations x 2 K-tiles, 4 merged phases ----
    for (int t = 0; t < 96; ++t) {
        const int kt1 = 2 * t + 1;
        const int sA  = (2 * t + 2 < NKT) ? 2 * t + 2 : NKT - 1;  // clamp: staged-
        const int sB  = (2 * t + 3 < NKT) ? 2 * t + 3 : NKT - 1;  // never-read tail

        // Phase I: buf0-klo (ks=0), 32 MFMA
        READ_AF(af0, 0, 0, 0); READ_AF(af1, 0, 0, 1); READ_B(0, 0);
        STAGE_A(1, 1, kt1);
        BARX();
        MFMA16(af0, 0);
        STAGE_B(0, 0, sA);
        MFMA16(af1, 1);
        BARX();

        // Phase II: buf0-khi (ks=1), 32 MFMA; counted vmcnt mid-cluster
        READ_AF(af1, 0, 1, 1); READ_AF(af0, 0, 1, 0); READ_B(0, 1);
        STAGE_A(0, 0, sA);
        BARX();
        MFMA16(af1, 1);
        STAGE_B(0, 1, sA);
        VM6();
        MFMA16(af0, 0);
        BARX();

        // Phase III: buf1-klo, 32 MFMA
        READ_AF(af0, 1, 0, 0); READ_AF(af1, 1, 0, 1); READ_B(1, 0);
        STAGE_A(0, 1, sA);
        BARX();
        MFMA16(af0, 0);
        STAGE_B(1, 0, sB);
        MFMA16(af1, 1);
        BARX();

        // Phase IV: buf1-khi, 32 MFMA; counted vmcnt mid-cluster
        READ_AF(af1, 1, 1, 1); READ_AF(af0, 1, 1, 0); READ_B(1, 1);
        STAGE_A(1, 0, sB);
        BARX();
        MFMA16(af1, 1);
        STAGE_B(1, 1, sB);
        VM6();
        MFMA16(af0, 0);
        BARX();
    }

    // ---- epilogue: C/D layout col = lane&15, row = quad*4 + reg ----
    #pragma unroll
    for (int fi = 0; fi < 8; ++fi) {
        #pragma unroll
        for (int nj = 0; nj < 4; ++nj) {
            const int col  = n0 + wn * 64 + nj * 16 + r;
            const int rowb = m0 + wm * 128 + fi * 16 + quad * 4;
            #pragma unroll
            for (int reg = 0; reg < 4; ++reg)
                OUT[(size_t)(rowb + reg) * NOUT + col] = acc[fi][nj][reg];
        }
    }
#undef BARX
#undef VM6
#undef STAGE_A
#undef STAGE_B
#undef READ_AF
#undef READ_B
#undef MFMA16
}

// ---------------- fallback: validated round-2 fused kernel ----------------
#define BM 128
#define BN 128
#define NF 16
#define BK 96
#define LDK 104

__global__ __launch_bounds__(256)
void kan_fused(const float* __restrict__ X, const float* __restrict__ BW,
               const float* __restrict__ SW, float* __restrict__ OUT)
{
    __shared__ __align__(16) unsigned short As[BM * LDK];
    __shared__ __align__(16) unsigned short Bs[BN * LDK];

    const int tid  = threadIdx.x;
    const int lane = tid & 63;
    const int wave = tid >> 6;
    const int mt = blockIdx.x >> 4;
    const int nt = blockIdx.x & 15;
    const int m0 = mt * BM;
    const int n0 = nt * BN;
    const int r    = lane & 15;
    const int quad = lane >> 4;
    const int wm = (wave & 1) * 64;
    const int wn = (wave >> 1) * 64;

    f32x4 acc[4][4];
    #pragma unroll
    for (int i = 0; i < 4; ++i)
        #pragma unroll
        for (int j = 0; j < 4; ++j)
            acc[i][j] = (f32x4){0.0f, 0.0f, 0.0f, 0.0f};

    for (int it = 0; it < KIN / NF; ++it) {
        const int i0 = it * NF;
        __syncthreads();
        #pragma unroll
        for (int s = 0; s < 2; ++s) {
            const int slot = tid + s * 256;
            const int row  = slot >> 2;
            const int fq   = slot & 3;
            const f32x4 xv = *(const f32x4*)(X + (size_t)(m0 + row) * KIN + i0 + fq * 4);
            unsigned short basv[20];
            unsigned short silv[4];
            #pragma unroll
            for (int e = 0; e < 4; ++e) {
                const float xf = xv[e];
                silv[e] = f2bf(xf / (1.0f + __expf(-xf)));
                #pragma unroll
                for (int c = 0; c < 5; ++c) {
                    const float d = xf - (-1.0f + 0.5f * (float)c);
                    basv[e * 5 + c] = f2bf(__expf(-5.0f * d * d));
                }
            }
            unsigned short* dst = As + row * LDK + fq * 20;
            #pragma unroll
            for (int q = 0; q < 5; ++q) {
                u16x4 v;
                v.x = basv[q * 4 + 0]; v.y = basv[q * 4 + 1];
                v.z = basv[q * 4 + 2]; v.w = basv[q * 4 + 3];
                *(u16x4*)(dst + q * 4) = v;
            }
            u16x4 sv;
            sv.x = silv[0]; sv.y = silv[1]; sv.z = silv[2]; sv.w = silv[3];
            *(u16x4*)(As + row * LDK + 80 + fq * 4) = sv;
        }
        {
            const int orow = tid >> 1;
            const int half = tid & 1;
            const float* sbase = SW + (size_t)(n0 + orow) * (KIN * 5) + i0 * 5 + half * 40;
            unsigned short* brow = Bs + orow * LDK + half * 40;
            #pragma unroll
            for (int p = 0; p < 10; ++p) {
                const f32x4 wv = *(const f32x4*)(sbase + p * 4);
                u16x4 v;
                v.x = f2bf(wv.x); v.y = f2bf(wv.y);
                v.z = f2bf(wv.z); v.w = f2bf(wv.w);
                *(u16x4*)(brow + p * 4) = v;
            }
        }
        #pragma unroll
        for (int s = 0; s < 2; ++s) {
            const int slot = tid + s * 256;
            const int row  = slot >> 2;
            const int fq   = slot & 3;
            const f32x4 wv = *(const f32x4*)(BW + (size_t)(n0 + row) * KIN + i0 + fq * 4);
            u16x4 v;
            v.x = f2bf(wv.x); v.y = f2bf(wv.y);
            v.z = f2bf(wv.z); v.w = f2bf(wv.w);
            *(u16x4*)(Bs + row * LDK + 80 + fq * 4) = v;
        }
        __syncthreads();
        #pragma unroll
        for (int ks = 0; ks < 3; ++ks) {
            bf16x8 af[4], bfr[4];
            #pragma unroll
            for (int mi = 0; mi < 4; ++mi)
                af[mi] = *(const bf16x8*)(As + (wm + mi * 16 + r) * LDK + ks * 32 + quad * 8);
            #pragma unroll
            for (int ni = 0; ni < 4; ++ni)
                bfr[ni] = *(const bf16x8*)(Bs + (wn + ni * 16 + r) * LDK + ks * 32 + quad * 8);
            #pragma unroll
            for (int mi = 0; mi < 4; ++mi)
                #pragma unroll
                for (int ni = 0; ni < 4; ++ni)
                    acc[mi][ni] = __builtin_amdgcn_mfma_f32_16x16x32_bf16(
                        af[mi], bfr[ni], acc[mi][ni], 0, 0, 0);
        }
    }
    #pragma unroll
    for (int mi = 0; mi < 4; ++mi) {
        #pragma unroll
        for (int ni = 0; ni < 4; ++ni) {
            const int col  = n0 + wn + ni * 16 + r;
            const int rowb = m0 + wm + mi * 16 + quad * 4;
            #pragma unroll
            for (int reg = 0; reg < 4; ++reg)
                OUT[(size_t)(rowb + reg) * NOUT + col] = acc[mi][ni][reg];
        }
    }
}

extern "C" void kernel_launch(void* const* d_in, const int* in_sizes, int n_in,
                              void* d_out, int out_size, void* d_ws, size_t ws_size,
                              hipStream_t stream) {
    const float* X  = (const float*)d_in[0];
    const float* BW = (const float*)d_in[1];
    const float* SW = (const float*)d_in[2];
    float* OUT = (float*)d_out;

    const size_t nA = (size_t)BATCH * KEXP;          // 201,326,592 elems
    const size_t nW = (size_t)NOUT * KEXP;           //  25,165,824 elems
    const size_t ws_need = (nA + nW) * sizeof(__bf16);   // 452,984,832 B

    if (ws_size >= ws_need) {
        __bf16* Aexp = (__bf16*)d_ws;
        __bf16* Wexp = Aexp + nA;
        expand_ab<<<dim3(NOUT + BATCH), dim3(256), 0, stream>>>(X, BW, SW, Aexp, Wexp);
        gemm8<<<dim3(512), dim3(512), 0, stream>>>(Aexp, Wexp, OUT);
    } else {
        kan_fused<<<dim3(128 * 16), dim3(256), 0, stream>>>(X, BW, SW, OUT);
    }
}

// Round 5
// 963.614 us; speedup vs baseline: 1.0098x; 1.0098x over previous
//
#include <hip/hip_runtime.h>
#include <hip/hip_bf16.h>
#include <cstdint>
#include <cstddef>

// out[b,o] = sum_i silu(x[b,i])*BW[o,i] + sum_{i,c} exp(-5*(x[b,i]-g_c)^2)*SW[o,i,c]
// Round 8: fragment-prefetch pipelining. Round-4 proved phases are serialized
// (ds_read region + MFMA region don't overlap; model 52% vs measured 55% util).
// Now each phase's fragments are ds_read during the PREVIOUS phase's MFMA cluster:
// cluster entry needs no lgkm wait. Stage positions + vmcnt(6) ledger unchanged
// from the validated round-3 schedule. VM6-gated prefetches (III's frags, next-I's
// frags) are placed in the following head-gap (after the close barrier) so ALL
// waves' staging has drained -- in-cluster would race on other waves' portions.

#define KIN 2048
#define NOUT 2048
#define BATCH 16384
#define KEXP 12288          // 2048 * 6
#define NKT 192             // KEXP / 64

typedef __bf16 bf16x8 __attribute__((ext_vector_type(8)));
typedef float f32x4 __attribute__((ext_vector_type(4)));
typedef unsigned short u16x4 __attribute__((ext_vector_type(4)));

__device__ __forceinline__ unsigned short f2bf(float f) {
    union { float f; uint32_t u; } v; v.f = f;
    return (unsigned short)((v.u + 0x7FFFu + ((v.u >> 16) & 1u)) >> 16);
}

__device__ __forceinline__ void load_lds16(const void* gptr, void* lptr) {
    __builtin_amdgcn_global_load_lds(
        (const __attribute__((address_space(1))) unsigned int*)gptr,
        (__attribute__((address_space(3))) unsigned int*)lptr,
        16, 0, 0);
}

// ---------------- merged expansion: one dispatch for Wexp + Aexp ----------------
__global__ __launch_bounds__(256)
void expand_ab(const float* __restrict__ X, const float* __restrict__ BW,
               const float* __restrict__ SW, __bf16* __restrict__ Aexp,
               __bf16* __restrict__ Wexp)
{
    __shared__ __align__(16) __bf16 rowbuf[KEXP];   // 24 KB
    const int bid = blockIdx.x;
    const int tid = threadIdx.x;

    if (bid >= NOUT) {
        // ---- A row: RBF ratio recurrence (2 exps for 5 basis values) + silu ----
        const int row = bid - NOUT;
        const float* xrow = X + (size_t)row * KIN;
        // k_c = exp(-5*g_c - 1.25), g_c = -1 + 0.5c
        const float K0 = 42.521082000062783f;   // exp(3.75)
        const float K1 = 3.4903429574597902f;   // exp(1.25)
        const float K2 = 0.2865047968601901f;   // exp(-1.25)
        const float K3 = 0.023517745856009107f; // exp(-3.75)
        #pragma unroll
        for (int s = 0; s < 2; ++s) {
            const f32x4 xv = *(const f32x4*)(xrow + (s * 256 + tid) * 4);
            float o[24];
            #pragma unroll
            for (int e = 0; e < 4; ++e) {
                const float xf = xv[e];
                const float d0 = xf + 1.0f;
                float b = __expf(-5.0f * d0 * d0);     // basis at g=-1
                const float s5 = __expf(5.0f * xf);    // ratio driver
                o[e * 6 + 0] = b;
                b *= s5 * K0; o[e * 6 + 1] = b;
                b *= s5 * K1; o[e * 6 + 2] = b;
                b *= s5 * K2; o[e * 6 + 3] = b;
                b *= s5 * K3; o[e * 6 + 4] = b;
                o[e * 6 + 5] = xf / (1.0f + __expf(-xf));
            }
            __bf16* dst = rowbuf + (s * 1024 + tid * 4) * 6;
            #pragma unroll
            for (int q = 0; q < 3; ++q) {
                bf16x8 v;
                #pragma unroll
                for (int t = 0; t < 8; ++t) v[t] = (__bf16)o[q * 8 + t];
                *(bf16x8*)(dst + q * 8) = v;
            }
        }
        __syncthreads();
        bf16x8* out = (bf16x8*)(Aexp + (size_t)row * KEXP);
        const bf16x8* lsrc = (const bf16x8*)rowbuf;
        #pragma unroll
        for (int t = 0; t < 6; ++t)
            out[tid + t * 256] = lsrc[tid + t * 256];
    } else {
        // ---- W row: interleave SW (5/elem) + BW (1/elem) ----
        const int orow = bid;
        #pragma unroll
        for (int s = 0; s < 2; ++s) {
            const int i0 = s * 1024 + tid * 4;
            const float* sb = SW + ((size_t)orow * KIN + i0) * 5;   // 20 floats
            const f32x4 bw = *(const f32x4*)(BW + (size_t)orow * KIN + i0);
            float sw[20];
            #pragma unroll
            for (int q = 0; q < 5; ++q) {
                const f32x4 v = *(const f32x4*)(sb + q * 4);
                sw[q * 4 + 0] = v.x; sw[q * 4 + 1] = v.y;
                sw[q * 4 + 2] = v.z; sw[q * 4 + 3] = v.w;
            }
            __bf16* dst = rowbuf + (size_t)i0 * 6;
            #pragma unroll
            for (int q = 0; q < 3; ++q) {
                bf16x8 v;
                #pragma unroll
                for (int t = 0; t < 8; ++t) {
                    const int e = (q * 8 + t) / 6;
                    const int c = (q * 8 + t) % 6;
                    v[t] = (c < 5) ? (__bf16)sw[e * 5 + c] : (__bf16)bw[e];
                }
                *(bf16x8*)(dst + q * 8) = v;
            }
        }
        __syncthreads();
        bf16x8* out = (bf16x8*)(Wexp + (size_t)orow * KEXP);
        const bf16x8* lsrc = (const bf16x8*)rowbuf;
        #pragma unroll
        for (int t = 0; t < 6; ++t)
            out[tid + t * 256] = lsrc[tid + t * 256];
    }
}

// ---------------- 256x256 pipelined GEMM: OUT[16384][2048] = Aexp * Wexp^T ------
// 4 phases/iter (2 K-tiles, BK=64). Fragments for phase p+1 are read inside
// phase p's MFMA cluster (hidden); cluster entry has zero lgkm dependency.
// Stage-issue points and vmcnt(6) placement = validated round-3 ledger:
//   entering I: 6 in flight {B1l,A1l,B1h}(kt 2t+1). I: +A1h(kt1) +B0l(sA);
//   II: +A0l +B0h, VM6 -> drains buf1 (ready III/IV). III: +A0h +B1l(sB);
//   IV: +A1l +B1h, VM6 -> drains buf0 k=sA (ready next I/II). Never vmcnt(0).
// Prefetch gating: slots drained by THIS region's VM6 (III's frags during II,
// next-I's frags during IV) are read in the NEXT head-gap -- after the close
// barrier every wave has passed its VM6, so all staging portions have landed.
// WAR: every slot's last read precedes its next stage by >=1 barrier (audited).
// Per-acc accumulation order unchanged -> output bitwise identical to round 3.
__global__ __launch_bounds__(512, 2)
void gemm8(const __bf16* __restrict__ A, const __bf16* __restrict__ W,
           float* __restrict__ OUT)
{
    __shared__ __align__(16) __bf16 LDS[65536];   // 128 KiB
    __bf16* LA = LDS;              // [2buf][2kh][8192 elems]
    __bf16* LB = LDS + 32768;

    const int tid  = threadIdx.x;
    const int lane = tid & 63;
    const int wave = tid >> 6;     // 0..7
    const int r    = lane & 15;
    const int quad = lane >> 4;
    const int wm   = wave >> 2;    // 0..1  (M)
    const int wn   = wave & 3;     // 0..3  (N)

    // T1 XCD-aware bijective swizzle: 512 blocks, 8 XCDs, chunk = 64.
    const int bid0 = blockIdx.x;
    const int bid  = (bid0 & 7) * 64 + (bid0 >> 3);
    const int mt  = bid >> 3;      // 64 m-tiles
    const int nt  = bid & 7;       // 8 n-tiles
    const int m0  = mt * 256;
    const int n0  = nt * 256;

    // ---- staging source addresses (per-lane, pre-swizzled) ----
    const int c0   = tid;                          // slot chunk ids 0..511
    const int c1   = tid + 512;                    // 512..1023
    const int row0 = c0 >> 2, row1 = c1 >> 2;      // slot rows 0..255
    const int j0   = (c0 & 3) ^ ((c0 >> 3) & 3);   // logical chunk for phys slot
    const int j1   = (c1 & 3) ^ ((c1 >> 3) & 3);
    const __bf16* srcA0 = A + (size_t)(m0 + row0) * KEXP + j0 * 8;
    const __bf16* srcA1 = A + (size_t)(m0 + row1) * KEXP + j1 * 8;
    const __bf16* srcB0 = W + (size_t)(n0 + row0) * KEXP + j0 * 8;
    const __bf16* srcB1 = W + (size_t)(n0 + row1) * KEXP + j1 * 8;

    // LDS stage destinations: wave-uniform base; HW adds lane*16B.
    const int dst0 = wave * 512;          // issue s=0 (elems)
    const int dst1 = 4096 + wave * 512;   // issue s=1

    // ---- fragment read bases (swizzled) ----
    const int swz = (quad ^ ((r >> 1) & 3)) * 8;
    const __bf16* a_rd = LA + (wm * 128 + r) * 32 + swz;
    const __bf16* b_rd = LB + (wn * 64 + r) * 32 + swz;

    f32x4 acc[8][4];
    #pragma unroll
    for (int i = 0; i < 8; ++i)
        #pragma unroll
        for (int j = 0; j < 4; ++j)
            acc[i][j] = (f32x4){0.0f, 0.0f, 0.0f, 0.0f};

    bf16x8 afX[4], afY[4], bfA[4], bfB[4];

#define BARX() asm volatile("s_barrier" ::: "memory")
#define VM6()  asm volatile("s_waitcnt vmcnt(6)" ::: "memory")

#define STAGE_A(buf, kh, kt) do { \
    const size_t ko = (size_t)(kt) * 64 + (kh) * 32; \
    load_lds16(srcA0 + ko, LA + ((buf) * 2 + (kh)) * 8192 + dst0); \
    load_lds16(srcA1 + ko, LA + ((buf) * 2 + (kh)) * 8192 + dst1); } while (0)

#define STAGE_B(buf, kh, kt) do { \
    const size_t ko = (size_t)(kt) * 64 + (kh) * 32; \
    load_lds16(srcB0 + ko, LB + ((buf) * 2 + (kh)) * 8192 + dst0); \
    load_lds16(srcB1 + ko, LB + ((buf) * 2 + (kh)) * 8192 + dst1); } while (0)

#define READ_A(arr, buf, ks, a) do { \
    const __bf16* p_ = a_rd + ((buf) * 2 + (ks)) * 8192 + (a) * 2048; \
    arr[0] = *(const bf16x8*)(p_); \
    arr[1] = *(const bf16x8*)(p_ + 512); \
    arr[2] = *(const bf16x8*)(p_ + 1024); \
    arr[3] = *(const bf16x8*)(p_ + 1536); } while (0)

#define READ_BF(arr, buf, ks) do { \
    const __bf16* p_ = b_rd + ((buf) * 2 + (ks)) * 8192; \
    arr[0] = *(const bf16x8*)(p_); \
    arr[1] = *(const bf16x8*)(p_ + 512); \
    arr[2] = *(const bf16x8*)(p_ + 1024); \
    arr[3] = *(const bf16x8*)(p_ + 1536); } while (0)

#define MFMA16(frag, bfr, a) do { \
    __builtin_amdgcn_s_setprio(1); \
    _Pragma("unroll") \
    for (int mi_ = 0; mi_ < 4; ++mi_) { \
        _Pragma("unroll") \
        for (int nj_ = 0; nj_ < 4; ++nj_) \
            acc[(a) * 4 + mi_][nj_] = __builtin_amdgcn_mfma_f32_16x16x32_bf16( \
                frag[mi_], bfr[nj_], acc[(a) * 4 + mi_][nj_], 0, 0, 0); \
    } \
    __builtin_amdgcn_s_setprio(0); } while (0)

    // ---- prologue: K-tile 0 full (buf0) + 3 of K-tile 1 (buf1) = 14 loads ----
    STAGE_B(0, 0, 0); STAGE_A(0, 0, 0); STAGE_B(0, 1, 0); STAGE_A(0, 1, 0);
    STAGE_B(1, 0, 1); STAGE_A(1, 0, 1); STAGE_B(1, 1, 1);
    VM6();            // completes the 4 buf0 slots; leaves buf1's 3 in flight
    BARX();
    // phase-I operands (buf0-klo): drained by prologue VM6 + barrier -> safe
    READ_A(afX, 0, 0, 0);
    READ_BF(bfA, 0, 0);

    // ---- main loop: 96 iterations x 2 K-tiles, 4 pipelined phases ----
    for (int t = 0; t < 96; ++t) {
        const int kt1 = 2 * t + 1;
        const int sA  = (2 * t + 2 < NKT) ? 2 * t + 2 : NKT - 1;  // clamp: staged-
        const int sB  = (2 * t + 3 < NKT) ? 2 * t + 3 : NKT - 1;  // never-read tail

        // ---- phase I: buf0-klo. Entry operands already in regs. ----
        STAGE_A(1, 1, kt1);
        BARX();
        READ_A(afY, 0, 0, 1);              // 2nd A-half, hidden under MFMA
        MFMA16(afX, bfA, 0);
        STAGE_B(0, 0, sA);
        READ_A(afX, 0, 1, 0);              // phase-II A (slot drained prev IV-VM6)
        READ_BF(bfB, 0, 1);                // phase-II B
        MFMA16(afY, bfA, 1);
        BARX();

        // ---- phase II: buf0-khi ----
        STAGE_A(0, 0, sA);
        BARX();
        READ_A(afY, 0, 1, 1);
        MFMA16(afX, bfB, 0);
        STAGE_B(0, 1, sA);
        VM6();                             // drains buf1 (kt1) for III/IV
        MFMA16(afY, bfB, 1);
        BARX();

        // ---- phase III gap: VM6-gated prefetch (all waves past VM6 now) ----
        STAGE_A(0, 1, sA);
        READ_A(afX, 1, 0, 0);              // phase-III A
        READ_BF(bfA, 1, 0);                // phase-III B
        BARX();
        READ_A(afY, 1, 0, 1);
        MFMA16(afX, bfA, 0);
        STAGE_B(1, 0, sB);
        READ_A(afX, 1, 1, 0);              // phase-IV A (drained II-VM6 + barrier)
        READ_BF(bfB, 1, 1);                // phase-IV B
        MFMA16(afY, bfA, 1);
        BARX();

        // ---- phase IV: buf1-khi ----
        STAGE_A(1, 0, sB);
        BARX();
        READ_A(afY, 1, 1, 1);
        MFMA16(afX, bfB, 0);
        STAGE_B(1, 1, sB);
        VM6();                             // drains buf0 (sA) for next I/II
        MFMA16(afY, bfB, 1);
        BARX();

        // ---- next-I gap prefetch: VM6-gated, all waves past IV-VM6 ----
        READ_A(afX, 0, 0, 0);
        READ_BF(bfA, 0, 0);
    }

    // ---- epilogue: C/D layout col = lane&15, row = quad*4 + reg ----
    #pragma unroll
    for (int fi = 0; fi < 8; ++fi) {
        #pragma unroll
        for (int nj = 0; nj < 4; ++nj) {
            const int col  = n0 + wn * 64 + nj * 16 + r;
            const int rowb = m0 + wm * 128 + fi * 16 + quad * 4;
            #pragma unroll
            for (int reg = 0; reg < 4; ++reg)
                OUT[(size_t)(rowb + reg) * NOUT + col] = acc[fi][nj][reg];
        }
    }
#undef BARX
#undef VM6
#undef STAGE_A
#undef STAGE_B
#undef READ_A
#undef READ_BF
#undef MFMA16
}

// ---------------- fallback: validated round-2 fused kernel ----------------
#define BM 128
#define BN 128
#define NF 16
#define BK 96
#define LDK 104

__global__ __launch_bounds__(256)
void kan_fused(const float* __restrict__ X, const float* __restrict__ BW,
               const float* __restrict__ SW, float* __restrict__ OUT)
{
    __shared__ __align__(16) unsigned short As[BM * LDK];
    __shared__ __align__(16) unsigned short Bs[BN * LDK];

    const int tid  = threadIdx.x;
    const int lane = tid & 63;
    const int wave = tid >> 6;
    const int mt = blockIdx.x >> 4;
    const int nt = blockIdx.x & 15;
    const int m0 = mt * BM;
    const int n0 = nt * BN;
    const int r    = lane & 15;
    const int quad = lane >> 4;
    const int wm = (wave & 1) * 64;
    const int wn = (wave >> 1) * 64;

    f32x4 acc[4][4];
    #pragma unroll
    for (int i = 0; i < 4; ++i)
        #pragma unroll
        for (int j = 0; j < 4; ++j)
            acc[i][j] = (f32x4){0.0f, 0.0f, 0.0f, 0.0f};

    for (int it = 0; it < KIN / NF; ++it) {
        const int i0 = it * NF;
        __syncthreads();
        #pragma unroll
        for (int s = 0; s < 2; ++s) {
            const int slot = tid + s * 256;
            const int row  = slot >> 2;
            const int fq   = slot & 3;
            const f32x4 xv = *(const f32x4*)(X + (size_t)(m0 + row) * KIN + i0 + fq * 4);
            unsigned short basv[20];
            unsigned short silv[4];
            #pragma unroll
            for (int e = 0; e < 4; ++e) {
                const float xf = xv[e];
                silv[e] = f2bf(xf / (1.0f + __expf(-xf)));
                #pragma unroll
                for (int c = 0; c < 5; ++c) {
                    const float d = xf - (-1.0f + 0.5f * (float)c);
                    basv[e * 5 + c] = f2bf(__expf(-5.0f * d * d));
                }
            }
            unsigned short* dst = As + row * LDK + fq * 20;
            #pragma unroll
            for (int q = 0; q < 5; ++q) {
                u16x4 v;
                v.x = basv[q * 4 + 0]; v.y = basv[q * 4 + 1];
                v.z = basv[q * 4 + 2]; v.w = basv[q * 4 + 3];
                *(u16x4*)(dst + q * 4) = v;
            }
            u16x4 sv;
            sv.x = silv[0]; sv.y = silv[1]; sv.z = silv[2]; sv.w = silv[3];
            *(u16x4*)(As + row * LDK + 80 + fq * 4) = sv;
        }
        {
            const int orow = tid >> 1;
            const int half = tid & 1;
            const float* sbase = SW + (size_t)(n0 + orow) * (KIN * 5) + i0 * 5 + half * 40;
            unsigned short* brow = Bs + orow * LDK + half * 40;
            #pragma unroll
            for (int p = 0; p < 10; ++p) {
                const f32x4 wv = *(const f32x4*)(sbase + p * 4);
                u16x4 v;
                v.x = f2bf(wv.x); v.y = f2bf(wv.y);
                v.z = f2bf(wv.z); v.w = f2bf(wv.w);
                *(u16x4*)(brow + p * 4) = v;
            }
        }
        #pragma unroll
        for (int s = 0; s < 2; ++s) {
            const int slot = tid + s * 256;
            const int row  = slot >> 2;
            const int fq   = slot & 3;
            const f32x4 wv = *(const f32x4*)(BW + (size_t)(n0 + row) * KIN + i0 + fq * 4);
            u16x4 v;
            v.x = f2bf(wv.x); v.y = f2bf(wv.y);
            v.z = f2bf(wv.z); v.w = f2bf(wv.w);
            *(u16x4*)(Bs + row * LDK + 80 + fq * 4) = v;
        }
        __syncthreads();
        #pragma unroll
        for (int ks = 0; ks < 3; ++ks) {
            bf16x8 af[4], bfr[4];
            #pragma unroll
            for (int mi = 0; mi < 4; ++mi)
                af[mi] = *(const bf16x8*)(As + (wm + mi * 16 + r) * LDK + ks * 32 + quad * 8);
            #pragma unroll
            for (int ni = 0; ni < 4; ++ni)
                bfr[ni] = *(const bf16x8*)(Bs + (wn + ni * 16 + r) * LDK + ks * 32 + quad * 8);
            #pragma unroll
            for (int mi = 0; mi < 4; ++mi)
                #pragma unroll
                for (int ni = 0; ni < 4; ++ni)
                    acc[mi][ni] = __builtin_amdgcn_mfma_f32_16x16x32_bf16(
                        af[mi], bfr[ni], acc[mi][ni], 0, 0, 0);
        }
    }
    #pragma unroll
    for (int mi = 0; mi < 4; ++mi) {
        #pragma unroll
        for (int ni = 0; ni < 4; ++ni) {
            const int col  = n0 + wn + ni * 16 + r;
            const int rowb = m0 + wm + mi * 16 + quad * 4;
            #pragma unroll
            for (int reg = 0; reg < 4; ++reg)
                OUT[(size_t)(rowb + reg) * NOUT + col] = acc[mi][ni][reg];
        }
    }
}

extern "C" void kernel_launch(void* const* d_in, const int* in_sizes, int n_in,
                              void* d_out, int out_size, void* d_ws, size_t ws_size,
                              hipStream_t stream) {
    const float* X  = (const float*)d_in[0];
    const float* BW = (const float*)d_in[1];
    const float* SW = (const float*)d_in[2];
    float* OUT = (float*)d_out;

    const size_t nA = (size_t)BATCH * KEXP;          // 201,326,592 elems
    const size_t nW = (size_t)NOUT * KEXP;           //  25,165,824 elems
    const size_t ws_need = (nA + nW) * sizeof(__bf16);   // 452,984,832 B

    if (ws_size >= ws_need) {
        __bf16* Aexp = (__bf16*)d_ws;
        __bf16* Wexp = Aexp + nA;
        expand_ab<<<dim3(NOUT + BATCH), dim3(256), 0, stream>>>(X, BW, SW, Aexp, Wexp);
        gemm8<<<dim3(512), dim3(512), 0, stream>>>(Aexp, Wexp, OUT);
    } else {
        kan_fused<<<dim3(128 * 16), dim3(256), 0, stream>>>(X, BW, SW, OUT);
    }
}